// Round 25
// baseline (163.161 us; speedup 1.0000x reference)
//
#include <hip/hip_runtime.h>
#include <math.h>

#define NN 50000
#define EE 800000

typedef __attribute__((ext_vector_type(8))) short short8;
typedef __attribute__((ext_vector_type(4))) float f32x4;
typedef __attribute__((ext_vector_type(2))) float f32x2;

__device__ inline float b2f(unsigned u16) {
    union { unsigned i; float f; } v; v.i = (u16 & 0xFFFFu) << 16; return v.f;
}
__device__ inline unsigned short f2b(float f) {
    unsigned u = __float_as_uint(f);
    unsigned r = (u + 0x7FFFu + ((u >> 16) & 1u)) >> 16;   // RNE
    return (unsigned short)r;
}
__device__ inline unsigned cvt_pk_bf16(float lo, float hi) {
    unsigned r;
    asm("v_cvt_pk_bf16_f32 %0, %1, %2" : "=v"(r) : "v"(lo), "v"(hi));
    return r;
}
__device__ inline void gload16(const unsigned short* g, unsigned short* l) {
    __builtin_amdgcn_global_load_lds(
        (const __attribute__((address_space(1))) void*)g,
        (__attribute__((address_space(3))) void*)l, 16, 0, 0);
}

// ---------------------------------------------------------------------------
// prep: WEIGHTS ONLY (rank atomics moved into fused3) + tnorm/lsep.
// W_t perm: tile-col cp feeds output byte b=(cp&~63)|((cp&15)*4)|((cp>>4)&3).
// ---------------------------------------------------------------------------
#define PREP_THREADS (65536 + 32768 + 16384 + 2048)

__global__ __launch_bounds__(256) void prep_k(const float* __restrict__ W,
                                              const float* __restrict__ W1,
                                              const float* __restrict__ W2,
                                              const float* __restrict__ W_phi,
                                              const float* __restrict__ tilde_phi,
                                              unsigned short* __restrict__ W_t,
                                              unsigned short* __restrict__ W1_bf,
                                              unsigned short* __restrict__ W2_bf,
                                              unsigned short* __restrict__ Wphi_t,
                                              float* __restrict__ tnorm,
                                              float* __restrict__ lsep_out) {
    if (blockIdx.x == 0) {
        __shared__ float tn[64];
        int t = threadIdx.x;
        if (t < 64) {
            float v = tilde_phi[t];
            float sq = v * v;
            #pragma unroll
            for (int s = 8; s; s >>= 1) sq += __shfl_xor(sq, s, 16);
            float tnv = v / sqrtf(sq);
            tn[t] = tnv;
            tnorm[t] = tnv;
        }
        __syncthreads();
        if (t == 0) {
            float tot = 0.f;
            for (int a = 0; a < 4; ++a)
                for (int b = 0; b < 4; ++b) {
                    float s2 = 0.f;
                    for (int p = 0; p < 16; ++p) {
                        float df = tn[a * 16 + p] - tn[b * 16 + p];
                        s2 += df * df;
                    }
                    tot += s2;
                }
            lsep_out[0] = tot * 0.25f;
        }
    }
    int i = blockIdx.x * 256 + threadIdx.x;
    if (i < 65536) {
        int cp = i >> 8, r = i & 255;
        int b = (cp & ~63) | ((cp & 15) * 4) | ((cp >> 4) & 3);
        int ch = b >> 2, k = b & 3;
        W_t[i] = f2b(W[(size_t)r * 256 + (k << 6) + ch]);
    } else if (i < 98304) {
        int j = i - 65536;
        W1_bf[j] = f2b(W1[j]);
    } else if (i < 114688) {
        int j = i - 98304;
        W2_bf[j] = f2b(W2[j]);
    } else if (i < 116736) {
        int j = i - 114688;
        int cp = j >> 7, r = j & 127;
        Wphi_t[j] = (cp < 15) ? f2b(W_phi[(size_t)r * 15 + cp]) : (unsigned short)0;
    }
}

// ---------------------------------------------------------------------------
// h-GEMM branch: BM=128, BN=128, KD=256, 512 thr (8 waves, 4x2), AM=2, AN=4.
// DOUBLE-BUFFERED: one barrier per K-step. 32KB of the union.
// ---------------------------------------------------------------------------
__device__ __forceinline__ void hgemm8_body(unsigned short* lds,
                                            const float* __restrict__ A,
                                            const unsigned short* __restrict__ Bt,
                                            unsigned int* __restrict__ h8w,
                                            int bxm, int bxn) {
    unsigned short* As = lds;           // [2][4096]
    unsigned short* Bs = lds + 8192;    // [2][4096]
    const int tid = threadIdx.x;
    const int l = tid & 63, l15 = l & 15, l4 = l >> 4;
    const int w = tid >> 6;
    const int wr = w >> 1, wc = w & 1;
    const int row0 = bxm * 128, col0 = bxn * 128;
    const int wrow = wr * 32, wcol = wc * 64;

    const int r_ = tid >> 2, s_ = tid & 3;
    int gr_ = row0 + r_; if (gr_ >= NN) gr_ = NN - 1;

    auto stage = [&](int buf, int k0) {
        const float* Af = A + (size_t)gr_ * 256 + k0 + s_ * 8;
        float4 f0 = *(const float4*)Af, f1 = *(const float4*)(Af + 4);
        *(uint4*)&As[buf * 4096 + tid * 8] =
            make_uint4(cvt_pk_bf16(f0.x, f0.y), cvt_pk_bf16(f0.z, f0.w),
                       cvt_pk_bf16(f1.x, f1.y), cvt_pk_bf16(f1.z, f1.w));
        gload16(&Bt[(size_t)(col0 + r_) * 256 + k0 + s_ * 8],
                &Bs[buf * 4096 + (tid - l) * 8]);
    };

    f32x4 acc[2][4];
    #pragma unroll
    for (int m = 0; m < 2; ++m)
        #pragma unroll
        for (int n = 0; n < 4; ++n) acc[m][n] = (f32x4){0.f, 0.f, 0.f, 0.f};

    stage(0, 0);
    __syncthreads();
    int cur = 0;
    for (int t = 0; t < 8; ++t) {
        if (t + 1 < 8) stage(cur ^ 1, (t + 1) * 32);
        short8 af[2], bfr[4];
        #pragma unroll
        for (int m = 0; m < 2; ++m)
            af[m] = *(const short8*)&As[cur * 4096 + ((wrow + m * 16 + l15) * 4 + l4) * 8];
        #pragma unroll
        for (int n = 0; n < 4; ++n)
            bfr[n] = *(const short8*)&Bs[cur * 4096 + ((wcol + n * 16 + l15) * 4 + l4) * 8];
        #pragma unroll
        for (int m = 0; m < 2; ++m)
            #pragma unroll
            for (int n = 0; n < 4; ++n)
                acc[m][n] = __builtin_amdgcn_mfma_f32_16x16x32_bf16(af[m], bfr[n], acc[m][n], 0, 0, 0);
        if (t + 1 < 8) __syncthreads();
        cur ^= 1;
    }
    #pragma unroll
    for (int m = 0; m < 2; ++m)
        #pragma unroll
        for (int r = 0; r < 4; ++r) {
            int gr = row0 + wrow + m * 16 + l4 * 4 + r;
            if (gr >= NN) continue;
            unsigned pk = __builtin_amdgcn_cvt_pk_fp8_f32(acc[m][0][r], acc[m][1][r], 0, false);
            pk = __builtin_amdgcn_cvt_pk_fp8_f32(acc[m][2][r], acc[m][3][r], pk, true);
            h8w[(size_t)gr * 64 + ((col0 + wcol) >> 2) + l15] = pk;
        }
}

// ---------------------------------------------------------------------------
// hid+phi+delta branch: BM=64 rows of e_l. phi bf16, deltap bf16.
// ---------------------------------------------------------------------------
#define LDPAD 264

__device__ __forceinline__ void hiddelta_body(unsigned short* lds,
                                              const float* __restrict__ e_l,
                                              const unsigned short* __restrict__ W1_bf,
                                              const unsigned short* __restrict__ Wphi_t,
                                              const unsigned short* __restrict__ W2_bf,
                                              const float* __restrict__ b1,
                                              const float* __restrict__ b2,
                                              const float* __restrict__ tnorm,
                                              unsigned short* __restrict__ phi_b,
                                              unsigned short* __restrict__ deltap,
                                              float* __restrict__ lf_part, int bxm) {
    unsigned short* As = lds;            // [64][32]   (stage 1)
    unsigned short* Bs = lds + 2048;     // [256][32]  (stage 1)
    unsigned short* Wp = lds + 10240;    // [16][128]  (stage 1)
    unsigned short* hidL = lds;          // [64][264]  (stage 2, aliases above)
    const int tid = threadIdx.x;
    const int l = tid & 63, l15 = l & 15, l4 = l >> 4;
    const int w = tid >> 6;              // 0..7
    const int wr = w >> 1, wc = w & 1;
    const int row0 = bxm * 64;

    if (tid < 256) gload16(&Wphi_t[tid * 8], &Wp[(tid - l) * 8]);

    auto stage = [&](int k0) {
        if (tid < 256) {
            int o = tid, r = o >> 2, s = o & 3;
            int gr = row0 + r; if (gr >= NN) gr = NN - 1;
            const float* Af = e_l + (size_t)gr * 128 + k0 + s * 8;
            float4 f0 = *(const float4*)Af, f1 = *(const float4*)(Af + 4);
            *(uint4*)&As[o * 8] = make_uint4(cvt_pk_bf16(f0.x, f0.y), cvt_pk_bf16(f0.z, f0.w),
                                             cvt_pk_bf16(f1.x, f1.y), cvt_pk_bf16(f1.z, f1.w));
        }
        #pragma unroll
        for (int o = tid; o < 1024; o += 512) {
            int r = o >> 2, s = o & 3;
            gload16(&W1_bf[(size_t)r * 128 + k0 + s * 8], &Bs[(o - l) * 8]);
        }
    };

    f32x4 acc[8], pacc;
    #pragma unroll
    for (int n = 0; n < 8; ++n) acc[n] = (f32x4){0.f, 0.f, 0.f, 0.f};
    pacc = (f32x4){0.f, 0.f, 0.f, 0.f};

    stage(0);
    for (int t = 0; t < 4; ++t) {
        int k0 = t * 32;
        __syncthreads();
        short8 af = *(const short8*)&As[((wr * 16 + l15) * 4 + l4) * 8];
        short8 bfr[8];
        #pragma unroll
        for (int n = 0; n < 8; ++n)
            bfr[n] = *(const short8*)&Bs[((wc * 128 + n * 16 + l15) * 4 + l4) * 8];
        #pragma unroll
        for (int n = 0; n < 8; ++n)
            acc[n] = __builtin_amdgcn_mfma_f32_16x16x32_bf16(af, bfr[n], acc[n], 0, 0, 0);
        if (wc == 1) {
            short8 pf = *(const short8*)&Wp[l15 * 128 + k0 + l4 * 8];
            pacc = __builtin_amdgcn_mfma_f32_16x16x32_bf16(af, pf, pacc, 0, 0, 0);
        }
        if (t + 1 < 4) { __syncthreads(); stage((t + 1) * 32); }
    }

    __syncthreads();
    #pragma unroll
    for (int n = 0; n < 8; ++n) {
        int col = wc * 128 + n * 16 + l15;
        float bv = b1[col];
        #pragma unroll
        for (int r = 0; r < 4; ++r) {
            int row = wr * 16 + l4 * 4 + r;
            hidL[row * LDPAD + col] = f2b(fmaxf(acc[n][r] + bv, 0.f));
        }
    }
    if (wc == 1) {
        #pragma unroll
        for (int r = 0; r < 4; ++r) {
            int gr = row0 + wr * 16 + l4 * 4 + r;
            if (gr < NN) phi_b[(size_t)gr * 16 + l15] = f2b(pacc[r]);
        }
    }
    __syncthreads();

    f32x4 acc2[2];
    acc2[0] = (f32x4){0.f, 0.f, 0.f, 0.f};
    acc2[1] = (f32x4){0.f, 0.f, 0.f, 0.f};
    for (int kk = 0; kk < 8; ++kk) {
        int k0 = kk * 32;
        short8 a2 = *(const short8*)&hidL[(wr * 16 + l15) * LDPAD + k0 + l4 * 8];
        #pragma unroll
        for (int n = 0; n < 2; ++n) {
            int col = wc * 32 + n * 16 + l15;
            short8 b2f_ = *(const short8*)&W2_bf[(size_t)col * 256 + k0 + l4 * 8];
            acc2[n] = __builtin_amdgcn_mfma_f32_16x16x32_bf16(a2, b2f_, acc2[n], 0, 0, 0);
        }
    }
    float lf = 0.f;
    #pragma unroll
    for (int n = 0; n < 2; ++n) {
        int gc = wc * 32 + n * 16 + l15;
        float bv = b2[gc], tv = tnorm[gc];
        #pragma unroll
        for (int r = 0; r < 4; ++r) {
            int gr = row0 + wr * 16 + l4 * 4 + r;
            if (gr < NN) {
                float v = acc2[n][r] + bv;
                lf += v * v;
                deltap[(size_t)gr * 64 + gc] = f2b(v + tv);
            }
        }
    }
    #pragma unroll
    for (int s = 32; s; s >>= 1) lf += __shfl_xor(lf, s);
    __syncthreads();
    float* red = (float*)&lds[16896];
    if (l == 0) red[w] = lf;
    __syncthreads();
    if (tid == 0) {
        float t_ = 0.f;
        #pragma unroll
        for (int j = 0; j < 8; ++j) t_ += red[j];
        lf_part[bxm] = t_;
    }
}

// ---------------------------------------------------------------------------
// merged dispatch, 512 threads.
//   [0,782)      h-GEMM (dbuf)
//   [782,1564)   hid+phi+delta
//   [1564,1955)  rank/degree atomics (hidden under GEMM latency)
// ---------------------------------------------------------------------------
__global__ __launch_bounds__(512) void fused3_k(const float* __restrict__ e_l,
                                                const float* __restrict__ h_l,
                                                const unsigned short* __restrict__ W1_bf,
                                                const unsigned short* __restrict__ Wphi_t,
                                                const unsigned short* __restrict__ W_t,
                                                const unsigned short* __restrict__ W2_bf,
                                                const float* __restrict__ b1,
                                                const float* __restrict__ b2,
                                                const float* __restrict__ tnorm,
                                                unsigned short* __restrict__ phi_b,
                                                unsigned int* __restrict__ h8w,
                                                unsigned short* __restrict__ deltap,
                                                float* __restrict__ lf_part,
                                                const int* __restrict__ dst,
                                                int* __restrict__ deg,
                                                int* __restrict__ rank) {
    __shared__ __align__(16) unsigned short lds[17408];   // 34.8 KB
    int bx = blockIdx.x;
    if (bx < 782) {
        hgemm8_body(lds, h_l, W_t, h8w, bx >> 1, bx & 1);
    } else if (bx < 1564) {
        hiddelta_body(lds, e_l, W1_bf, Wphi_t, W2_bf, b1, b2, tnorm,
                      phi_b, deltap, lf_part, bx - 782);
    } else {
        int base = (bx - 1564) * 2048 + threadIdx.x;
        #pragma unroll
        for (int j = 0; j < 4; ++j) {
            int e = base + j * 512;
            if (e < EE) rank[e] = atomicAdd(&deg[dst[e]], 1);
        }
    }
}

// ---------------------------------------------------------------------------
#define SCAN_NB ((NN + 255) / 256)   // 196
#define LF_NB 782

__global__ __launch_bounds__(256) void scan_partial_k(const int* __restrict__ deg,
                                                      int* __restrict__ bsum) {
    __shared__ int ws_[4];
    int i = blockIdx.x * 256 + threadIdx.x;
    int v = (i < NN) ? deg[i] : 0;
    int x = v;
    #pragma unroll
    for (int s = 32; s; s >>= 1) x += __shfl_xor(x, s);
    if ((threadIdx.x & 63) == 0) ws_[threadIdx.x >> 6] = x;
    __syncthreads();
    if (threadIdx.x == 0) bsum[blockIdx.x] = ws_[0] + ws_[1] + ws_[2] + ws_[3];
}

__global__ __launch_bounds__(256) void scan_bsum_k(int* __restrict__ bsum) {
    __shared__ int sd[256];
    int t = threadIdx.x;
    int v = (t < SCAN_NB) ? bsum[t] : 0;
    sd[t] = v;
    __syncthreads();
    for (int s = 1; s < 256; s <<= 1) {
        int u = (t >= s) ? sd[t - s] : 0;
        __syncthreads();
        sd[t] += u;
        __syncthreads();
    }
    if (t < SCAN_NB) bsum[t] = sd[t] - v;   // exclusive
}

__global__ __launch_bounds__(256) void scan_scatter_k(const int* __restrict__ deg,
                                                      const int* __restrict__ bsum,
                                                      int* __restrict__ offs,
                                                      unsigned short* __restrict__ csr_dst) {
    __shared__ int wexc[4];
    int i = blockIdx.x * 256 + threadIdx.x;
    int lane = threadIdx.x & 63, wid = threadIdx.x >> 6;
    int v = (i < NN) ? deg[i] : 0;
    int x = v;
    #pragma unroll
    for (int d = 1; d < 64; d <<= 1) { int u = __shfl_up(x, d); if (lane >= d) x += u; }
    if (lane == 63) wexc[wid] = x;
    __syncthreads();
    if (threadIdx.x == 0) {
        int a = wexc[0], b = wexc[1], c = wexc[2];
        wexc[0] = 0; wexc[1] = a; wexc[2] = a + b; wexc[3] = a + b + c;
    }
    __syncthreads();
    int excl = (x - v) + wexc[wid] + bsum[blockIdx.x];
    if (i < NN) {
        offs[i + 1] = excl + v;
        if (i == 0) offs[0] = 0;
        for (int q = excl; q < excl + v; ++q) csr_dst[q] = (unsigned short)i;
    }
}

// ---------------------------------------------------------------------------
// scatter: csr_src[offs[dst]+rank] = (ushort)src  (pure stores, ILP-4)
// ---------------------------------------------------------------------------
__global__ __launch_bounds__(512) void scatter_k(const int* __restrict__ src,
                                                 const int* __restrict__ dst,
                                                 const int* __restrict__ rank,
                                                 const int* __restrict__ offs,
                                                 unsigned short* __restrict__ csr_src) {
    int base = blockIdx.x * 2048 + threadIdx.x;
    int pos[4], sv[4];
    #pragma unroll
    for (int j = 0; j < 4; ++j) {
        int e = base + j * 512;
        if (e < EE) { pos[j] = offs[dst[e]] + rank[e]; sv[j] = src[e]; }
        else pos[j] = -1;
    }
    #pragma unroll
    for (int j = 0; j < 4; ++j)
        if (pos[j] >= 0) csr_src[pos[j]] = (unsigned short)sv[j];
}

// ---------------------------------------------------------------------------
// edge weights (thread per CSR slot); phi & deltap bf16; writes 4x bf16 (8B);
// block 3125 finalizes l_focus.
// ---------------------------------------------------------------------------
__global__ __launch_bounds__(256) void edge_w_k(const unsigned short* __restrict__ csr_src,
                                                const unsigned short* __restrict__ csr_dst,
                                                const unsigned short* __restrict__ phi_b,
                                                const unsigned short* __restrict__ deltap,
                                                uint2* __restrict__ csr_wb,
                                                const float* __restrict__ lfocus_part,
                                                float* __restrict__ lfocus_out) {
    if (blockIdx.x == 3125) {
        __shared__ float red[4];
        float s = 0.f;
        for (int i = threadIdx.x; i < LF_NB; i += 256) s += lfocus_part[i];
        #pragma unroll
        for (int st = 32; st; st >>= 1) s += __shfl_xor(s, st);
        if ((threadIdx.x & 63) == 0) red[threadIdx.x >> 6] = s;
        __syncthreads();
        if (threadIdx.x == 0)
            lfocus_out[0] = (red[0] + red[1] + red[2] + red[3]) * (1.f / ((float)NN * 4));
        return;
    }
    int e = blockIdx.x * 256 + threadIdx.x;
    if (e >= EE) return;
    int s = csr_src[e], d = csr_dst[e];
    float pv[16], qv[16];
    {
        const uint4* P = (const uint4*)(phi_b + (size_t)s * 16);
        uint4 x0 = P[0], x1 = P[1];
        unsigned xs[8] = {x0.x, x0.y, x0.z, x0.w, x1.x, x1.y, x1.z, x1.w};
        #pragma unroll
        for (int j = 0; j < 8; ++j) { pv[2 * j] = b2f(xs[j]); pv[2 * j + 1] = b2f(xs[j] >> 16); }
        const uint4* Q = (const uint4*)(phi_b + (size_t)d * 16);
        uint4 y0 = Q[0], y1 = Q[1];
        unsigned ys[8] = {y0.x, y0.y, y0.z, y0.w, y1.x, y1.y, y1.z, y1.w};
        #pragma unroll
        for (int j = 0; j < 8; ++j) { qv[2 * j] = b2f(ys[j]); qv[2 * j + 1] = b2f(ys[j] >> 16); }
    }
    float dv[16];
    float nrm2 = 0.f;
    #pragma unroll
    for (int p = 0; p < 15; ++p) {
        dv[p] = pv[p] - qv[p];
        nrm2 += dv[p] * dv[p];
    }
    float z = (nrm2 == 0.f) ? 1.f : 0.f;
    dv[15] = z;
    nrm2 += z;
    float inv = 1.f / fmaxf(sqrtf(nrm2), 1e-8f);
    const uint2* dl2 = (const uint2*)(deltap + (size_t)d * 64);
    float res[4];
    #pragma unroll
    for (int k = 0; k < 4; ++k) {
        float sacc = 0.f;
        #pragma unroll
        for (int q = 0; q < 4; ++q) {
            uint2 u = dl2[k * 4 + q];
            sacc += dv[q * 4 + 0] * b2f(u.x) + dv[q * 4 + 1] * b2f(u.x >> 16)
                  + dv[q * 4 + 2] * b2f(u.y) + dv[q * 4 + 3] * b2f(u.y >> 16);
        }
        res[k] = __expf(sacc * inv);
    }
    csr_wb[e] = make_uint2(cvt_pk_bf16(res[0], res[1]), cvt_pk_bf16(res[2], res[3]));
}

// ---------------------------------------------------------------------------
// per-dst aggregation, wave per node, lane = channel. csr_w is 4x bf16/edge.
// Wave-uniform weights/indices scalarized via readfirstlane.
// ---------------------------------------------------------------------------
__global__ __launch_bounds__(256) void aggregate_k(const int* __restrict__ offs,
                                                   const unsigned short* __restrict__ csr_src,
                                                   const unsigned int* __restrict__ csr_wu,
                                                   const unsigned int* __restrict__ h8,
                                                   const float* __restrict__ bias,
                                                   float* __restrict__ out) {
    int wave = threadIdx.x >> 6;
    int lane = threadIdx.x & 63;
    int n = blockIdx.x * 4 + wave;
    if (n >= NN) return;
    int beg = offs[n], end = offs[n + 1];

    // phase 1: denominators (coalesced flat read; uint parity = k-class pair)
    float pA = 0.f, pB = 0.f;
    for (int q = beg * 2 + lane; q < end * 2; q += 64) {
        unsigned u = csr_wu[q];
        pA += b2f(u);
        pB += b2f(u >> 16);
    }
    #pragma unroll
    for (int s = 2; s < 64; s <<= 1) { pA += __shfl_xor(pA, s); pB += __shfl_xor(pB, s); }
    float iA = (pA > 0.f) ? 1.f / pA : 0.f;
    float iB = (pB > 0.f) ? 1.f / pB : 0.f;
    float i0 = __shfl(iA, 0), i1 = __shfl(iB, 0);
    float i2 = __shfl(iA, 1), i3 = __shfl(iB, 1);

    // phase 2: weighted accumulation; weights & src idx scalarized
    const uint2* csr_w2 = (const uint2*)csr_wu;
    float a0 = 0.f, a1 = 0.f, a2 = 0.f, a3 = 0.f;
    int p = beg;
    for (; p + 3 < end; p += 4) {
        uint2 u0 = csr_w2[p], u1 = csr_w2[p + 1], u2 = csr_w2[p + 2], u3 = csr_w2[p + 3];
        int t0 = __builtin_amdgcn_readfirstlane((int)csr_src[p]);
        int t1 = __builtin_amdgcn_readfirstlane((int)csr_src[p + 1]);
        int t2 = __builtin_amdgcn_readfirstlane((int)csr_src[p + 2]);
        int t3 = __builtin_amdgcn_readfirstlane((int)csr_src[p + 3]);
        unsigned w0x = __builtin_amdgcn_readfirstlane(u0.x);
        unsigned w0y = __builtin_amdgcn_readfirstlane(u0.y);
        unsigned w1x = __builtin_amdgcn_readfirstlane(u1.x);
        unsigned w1y = __builtin_amdgcn_readfirstlane(u1.y);
        unsigned w2x = __builtin_amdgcn_readfirstlane(u2.x);
        unsigned w2y = __builtin_amdgcn_readfirstlane(u2.y);
        unsigned w3x = __builtin_amdgcn_readfirstlane(u3.x);
        unsigned w3y = __builtin_amdgcn_readfirstlane(u3.y);
        unsigned hv0 = h8[(size_t)t0 * 64 + lane];
        unsigned hv1 = h8[(size_t)t1 * 64 + lane];
        unsigned hv2 = h8[(size_t)t2 * 64 + lane];
        unsigned hv3 = h8[(size_t)t3 * 64 + lane];
        f32x2 lo, hi;
        lo = __builtin_amdgcn_cvt_pk_f32_fp8(hv0, false);
        hi = __builtin_amdgcn_cvt_pk_f32_fp8(hv0, true);
        a0 += b2f(w0x) * lo.x; a1 += b2f(w0x >> 16) * lo.y;
        a2 += b2f(w0y) * hi.x; a3 += b2f(w0y >> 16) * hi.y;
        lo = __builtin_amdgcn_cvt_pk_f32_fp8(hv1, false);
        hi = __builtin_amdgcn_cvt_pk_f32_fp8(hv1, true);
        a0 += b2f(w1x) * lo.x; a1 += b2f(w1x >> 16) * lo.y;
        a2 += b2f(w1y) * hi.x; a3 += b2f(w1y >> 16) * hi.y;
        lo = __builtin_amdgcn_cvt_pk_f32_fp8(hv2, false);
        hi = __builtin_amdgcn_cvt_pk_f32_fp8(hv2, true);
        a0 += b2f(w2x) * lo.x; a1 += b2f(w2x >> 16) * lo.y;
        a2 += b2f(w2y) * hi.x; a3 += b2f(w2y >> 16) * hi.y;
        lo = __builtin_amdgcn_cvt_pk_f32_fp8(hv3, false);
        hi = __builtin_amdgcn_cvt_pk_f32_fp8(hv3, true);
        a0 += b2f(w3x) * lo.x; a1 += b2f(w3x >> 16) * lo.y;
        a2 += b2f(w3y) * hi.x; a3 += b2f(w3y >> 16) * hi.y;
    }
    for (; p < end; ++p) {
        uint2 uA = csr_w2[p];
        int tA = __builtin_amdgcn_readfirstlane((int)csr_src[p]);
        unsigned wAx = __builtin_amdgcn_readfirstlane(uA.x);
        unsigned wAy = __builtin_amdgcn_readfirstlane(uA.y);
        unsigned hv = h8[(size_t)tA * 64 + lane];
        f32x2 lo = __builtin_amdgcn_cvt_pk_f32_fp8(hv, false);
        f32x2 hi = __builtin_amdgcn_cvt_pk_f32_fp8(hv, true);
        a0 += b2f(wAx) * lo.x; a1 += b2f(wAx >> 16) * lo.y;
        a2 += b2f(wAy) * hi.x; a3 += b2f(wAy >> 16) * hi.y;
    }
    float v = a0 * i0 + a1 * i1 + a2 * i2 + a3 * i3 + bias[lane];
    float nr = v * v;
    #pragma unroll
    for (int s = 32; s; s >>= 1) nr += __shfl_xor(nr, s);
    float invn = 1.f / fmaxf(sqrtf(nr), 1e-8f);
    out[(size_t)n * 64 + lane] = v * invn;
}

// ---------------------------------------------------------------------------
extern "C" void kernel_launch(void* const* d_in, const int* in_sizes, int n_in,
                              void* d_out, int out_size, void* d_ws, size_t ws_size,
                              hipStream_t stream) {
    const float* h_l       = (const float*)d_in[0];
    const float* e_l       = (const float*)d_in[1];
    const int*   src       = (const int*)d_in[2];
    const int*   dst       = (const int*)d_in[3];
    const float* W_phi     = (const float*)d_in[4];
    const float* W1        = (const float*)d_in[5];
    const float* b1        = (const float*)d_in[6];
    const float* W2        = (const float*)d_in[7];
    const float* b2        = (const float*)d_in[8];
    const float* tilde_phi = (const float*)d_in[9];
    const float* W         = (const float*)d_in[10];
    const float* bias      = (const float*)d_in[11];
    float* out = (float*)d_out;
    float* lsep_ptr   = out + (size_t)NN * 64;
    float* lfocus_ptr = out + (size_t)NN * 64 + 1;

    char* ws = (char*)d_ws;
    size_t off = 0;
    auto alloc = [&](size_t bytes) -> char* {
        char* p = ws + off;
        off += (bytes + 255) & ~(size_t)255;
        return p;
    };
    unsigned short* phi_b   = (unsigned short*)alloc((size_t)NN * 16 * 2);
    unsigned short* deltap  = (unsigned short*)alloc((size_t)NN * 64 * 2);
    unsigned int*   h8w     = (unsigned int*)alloc((size_t)NN * 256);
    unsigned short* csr_src = (unsigned short*)alloc((size_t)EE * 2);
    unsigned short* csr_dst = (unsigned short*)alloc((size_t)EE * 2);
    int*            rank    = (int*)alloc((size_t)EE * 4);
    uint2*          csr_wb  = (uint2*)alloc((size_t)EE * 8);
    int*            deg     = (int*)alloc((size_t)NN * 4);
    int*            offs    = (int*)alloc((size_t)(NN + 1) * 4);
    int*            bsum    = (int*)alloc((size_t)SCAN_NB * 4);
    float*          lf_part = (float*)alloc((size_t)LF_NB * 4);
    unsigned short* W_t     = (unsigned short*)alloc(256 * 256 * 2);
    unsigned short* W1_bf   = (unsigned short*)alloc(256 * 128 * 2);
    unsigned short* W2_bf   = (unsigned short*)alloc(64 * 256 * 2);
    unsigned short* Wphi_t  = (unsigned short*)alloc(16 * 128 * 2);
    float*          tnorm   = (float*)alloc(64 * 4);

    hipMemsetAsync(deg, 0, (size_t)NN * 4, stream);

    // prep: weights + tnorm/lsep (small; rank atomics moved into fused3)
    prep_k<<<(PREP_THREADS + 255) / 256, 256, 0, stream>>>(
        W, W1, W2, W_phi, tilde_phi,
        W_t, W1_bf, W2_bf, Wphi_t, tnorm, lsep_ptr);

    // merged: h-GEMM (dbuf) + hid+phi+delta + rank/degree atomics
    fused3_k<<<1955, 512, 0, stream>>>(e_l, h_l, W1_bf, Wphi_t, W_t, W2_bf,
                                       b1, b2, tnorm, phi_b, h8w, deltap, lf_part,
                                       dst, deg, rank);

    // CSR offsets (+ contiguous ushort csr_dst fill)
    scan_partial_k<<<SCAN_NB, 256, 0, stream>>>(deg, bsum);
    scan_bsum_k<<<1, 256, 0, stream>>>(bsum);
    scan_scatter_k<<<SCAN_NB, 256, 0, stream>>>(deg, bsum, offs, csr_dst);

    // scatter csr_src (rank-based, no atomics)
    scatter_k<<<391, 512, 0, stream>>>(src, dst, rank, offs, csr_src);

    // edge weights (bf16 phi/delta, bf16-packed out) + l_focus finalize
    edge_w_k<<<3126, 256, 0, stream>>>(csr_src, csr_dst, phi_b, deltap, csr_wb,
                                       lf_part, lfocus_ptr);

    // per-dst softmax + aggregation + normalize
    aggregate_k<<<12500, 256, 0, stream>>>(offs, csr_src, (const unsigned int*)csr_wb,
                                           h8w, bias, out);
}

// Round 26
// 159.719 us; speedup vs baseline: 1.0216x; 1.0216x over previous
//
#include <hip/hip_runtime.h>
#include <math.h>

#define NN 50000
#define EE 800000

typedef __attribute__((ext_vector_type(8))) short short8;
typedef __attribute__((ext_vector_type(4))) float f32x4;
typedef __attribute__((ext_vector_type(2))) float f32x2;

__device__ inline float b2f(unsigned u16) {
    union { unsigned i; float f; } v; v.i = (u16 & 0xFFFFu) << 16; return v.f;
}
__device__ inline unsigned short f2b(float f) {
    unsigned u = __float_as_uint(f);
    unsigned r = (u + 0x7FFFu + ((u >> 16) & 1u)) >> 16;   // RNE
    return (unsigned short)r;
}
__device__ inline unsigned cvt_pk_bf16(float lo, float hi) {
    unsigned r;
    asm("v_cvt_pk_bf16_f32 %0, %1, %2" : "=v"(r) : "v"(lo), "v"(hi));
    return r;
}
__device__ inline void gload16(const unsigned short* g, unsigned short* l) {
    __builtin_amdgcn_global_load_lds(
        (const __attribute__((address_space(1))) void*)g,
        (__attribute__((address_space(3))) void*)l, 16, 0, 0);
}

// ---------------------------------------------------------------------------
// prep: rank/degree atomics FIRST, then weight preps + tnorm/lsep.
// ---------------------------------------------------------------------------
#define PREP_THREADS (800000 + 65536 + 32768 + 16384 + 2048)

__global__ __launch_bounds__(256) void prep_k(const float* __restrict__ W,
                                              const float* __restrict__ W1,
                                              const float* __restrict__ W2,
                                              const float* __restrict__ W_phi,
                                              const float* __restrict__ tilde_phi,
                                              const int* __restrict__ dst,
                                              unsigned short* __restrict__ W_t,
                                              unsigned short* __restrict__ W1_bf,
                                              unsigned short* __restrict__ W2_bf,
                                              unsigned short* __restrict__ Wphi_t,
                                              int* __restrict__ deg,
                                              int* __restrict__ rank,
                                              float* __restrict__ tnorm,
                                              float* __restrict__ lsep_out) {
    if (blockIdx.x == 0) {
        __shared__ float tn[64];
        int t = threadIdx.x;
        if (t < 64) {
            float v = tilde_phi[t];
            float sq = v * v;
            #pragma unroll
            for (int s = 8; s; s >>= 1) sq += __shfl_xor(sq, s, 16);
            float tnv = v / sqrtf(sq);
            tn[t] = tnv;
            tnorm[t] = tnv;
        }
        __syncthreads();
        if (t == 0) {
            float tot = 0.f;
            for (int a = 0; a < 4; ++a)
                for (int b = 0; b < 4; ++b) {
                    float s2 = 0.f;
                    for (int p = 0; p < 16; ++p) {
                        float df = tn[a * 16 + p] - tn[b * 16 + p];
                        s2 += df * df;
                    }
                    tot += s2;
                }
            lsep_out[0] = tot * 0.25f;
        }
    }
    int i = blockIdx.x * 256 + threadIdx.x;
    if (i < 800000) {
        rank[i] = atomicAdd(&deg[dst[i]], 1);
    } else if (i < 865536) {
        int j = i - 800000;
        int cp = j >> 8, r = j & 255;
        int b = (cp & ~63) | ((cp & 15) * 4) | ((cp >> 4) & 3);
        int ch = b >> 2, k = b & 3;
        W_t[j] = f2b(W[(size_t)r * 256 + (k << 6) + ch]);
    } else if (i < 898304) {
        int j = i - 865536;
        W1_bf[j] = f2b(W1[j]);
    } else if (i < 914688) {
        int j = i - 898304;
        W2_bf[j] = f2b(W2[j]);
    } else if (i < 916736) {
        int j = i - 914688;
        int cp = j >> 7, r = j & 127;
        Wphi_t[j] = (cp < 15) ? f2b(W_phi[(size_t)r * 15 + cp]) : (unsigned short)0;
    }
}

// ---------------------------------------------------------------------------
// h-GEMM branch: BM=128, BN=128, KD=256, 512 thr (8 waves, 4x2), AM=2, AN=4.
// DOUBLE-BUFFERED: one barrier per K-step. 32KB of the union.
// ---------------------------------------------------------------------------
__device__ __forceinline__ void hgemm8_body(unsigned short* lds,
                                            const float* __restrict__ A,
                                            const unsigned short* __restrict__ Bt,
                                            unsigned int* __restrict__ h8w,
                                            int bxm, int bxn) {
    unsigned short* As = lds;           // [2][4096]
    unsigned short* Bs = lds + 8192;    // [2][4096]
    const int tid = threadIdx.x;
    const int l = tid & 63, l15 = l & 15, l4 = l >> 4;
    const int w = tid >> 6;
    const int wr = w >> 1, wc = w & 1;
    const int row0 = bxm * 128, col0 = bxn * 128;
    const int wrow = wr * 32, wcol = wc * 64;

    const int r_ = tid >> 2, s_ = tid & 3;
    int gr_ = row0 + r_; if (gr_ >= NN) gr_ = NN - 1;

    auto stage = [&](int buf, int k0) {
        const float* Af = A + (size_t)gr_ * 256 + k0 + s_ * 8;
        float4 f0 = *(const float4*)Af, f1 = *(const float4*)(Af + 4);
        *(uint4*)&As[buf * 4096 + tid * 8] =
            make_uint4(cvt_pk_bf16(f0.x, f0.y), cvt_pk_bf16(f0.z, f0.w),
                       cvt_pk_bf16(f1.x, f1.y), cvt_pk_bf16(f1.z, f1.w));
        gload16(&Bt[(size_t)(col0 + r_) * 256 + k0 + s_ * 8],
                &Bs[buf * 4096 + (tid - l) * 8]);
    };

    f32x4 acc[2][4];
    #pragma unroll
    for (int m = 0; m < 2; ++m)
        #pragma unroll
        for (int n = 0; n < 4; ++n) acc[m][n] = (f32x4){0.f, 0.f, 0.f, 0.f};

    stage(0, 0);
    __syncthreads();
    int cur = 0;
    for (int t = 0; t < 8; ++t) {
        if (t + 1 < 8) stage(cur ^ 1, (t + 1) * 32);
        short8 af[2], bfr[4];
        #pragma unroll
        for (int m = 0; m < 2; ++m)
            af[m] = *(const short8*)&As[cur * 4096 + ((wrow + m * 16 + l15) * 4 + l4) * 8];
        #pragma unroll
        for (int n = 0; n < 4; ++n)
            bfr[n] = *(const short8*)&Bs[cur * 4096 + ((wcol + n * 16 + l15) * 4 + l4) * 8];
        #pragma unroll
        for (int m = 0; m < 2; ++m)
            #pragma unroll
            for (int n = 0; n < 4; ++n)
                acc[m][n] = __builtin_amdgcn_mfma_f32_16x16x32_bf16(af[m], bfr[n], acc[m][n], 0, 0, 0);
        if (t + 1 < 8) __syncthreads();
        cur ^= 1;
    }
    #pragma unroll
    for (int m = 0; m < 2; ++m)
        #pragma unroll
        for (int r = 0; r < 4; ++r) {
            int gr = row0 + wrow + m * 16 + l4 * 4 + r;
            if (gr >= NN) continue;
            unsigned pk = __builtin_amdgcn_cvt_pk_fp8_f32(acc[m][0][r], acc[m][1][r], 0, false);
            pk = __builtin_amdgcn_cvt_pk_fp8_f32(acc[m][2][r], acc[m][3][r], pk, true);
            h8w[(size_t)gr * 64 + ((col0 + wcol) >> 2) + l15] = pk;
        }
}

// ---------------------------------------------------------------------------
// hid+phi+delta branch: BM=64 rows of e_l. phi bf16, deltap bf16.
// ---------------------------------------------------------------------------
#define LDPAD 264

__device__ __forceinline__ void hiddelta_body(unsigned short* lds,
                                              const float* __restrict__ e_l,
                                              const unsigned short* __restrict__ W1_bf,
                                              const unsigned short* __restrict__ Wphi_t,
                                              const unsigned short* __restrict__ W2_bf,
                                              const float* __restrict__ b1,
                                              const float* __restrict__ b2,
                                              const float* __restrict__ tnorm,
                                              unsigned short* __restrict__ phi_b,
                                              unsigned short* __restrict__ deltap,
                                              float* __restrict__ lf_part, int bxm) {
    unsigned short* As = lds;            // [64][32]   (stage 1)
    unsigned short* Bs = lds + 2048;     // [256][32]  (stage 1)
    unsigned short* Wp = lds + 10240;    // [16][128]  (stage 1)
    unsigned short* hidL = lds;          // [64][264]  (stage 2, aliases above)
    const int tid = threadIdx.x;
    const int l = tid & 63, l15 = l & 15, l4 = l >> 4;
    const int w = tid >> 6;              // 0..7
    const int wr = w >> 1, wc = w & 1;
    const int row0 = bxm * 64;

    if (tid < 256) gload16(&Wphi_t[tid * 8], &Wp[(tid - l) * 8]);

    auto stage = [&](int k0) {
        if (tid < 256) {
            int o = tid, r = o >> 2, s = o & 3;
            int gr = row0 + r; if (gr >= NN) gr = NN - 1;
            const float* Af = e_l + (size_t)gr * 128 + k0 + s * 8;
            float4 f0 = *(const float4*)Af, f1 = *(const float4*)(Af + 4);
            *(uint4*)&As[o * 8] = make_uint4(cvt_pk_bf16(f0.x, f0.y), cvt_pk_bf16(f0.z, f0.w),
                                             cvt_pk_bf16(f1.x, f1.y), cvt_pk_bf16(f1.z, f1.w));
        }
        #pragma unroll
        for (int o = tid; o < 1024; o += 512) {
            int r = o >> 2, s = o & 3;
            gload16(&W1_bf[(size_t)r * 128 + k0 + s * 8], &Bs[(o - l) * 8]);
        }
    };

    f32x4 acc[8], pacc;
    #pragma unroll
    for (int n = 0; n < 8; ++n) acc[n] = (f32x4){0.f, 0.f, 0.f, 0.f};
    pacc = (f32x4){0.f, 0.f, 0.f, 0.f};

    stage(0);
    for (int t = 0; t < 4; ++t) {
        int k0 = t * 32;
        __syncthreads();
        short8 af = *(const short8*)&As[((wr * 16 + l15) * 4 + l4) * 8];
        short8 bfr[8];
        #pragma unroll
        for (int n = 0; n < 8; ++n)
            bfr[n] = *(const short8*)&Bs[((wc * 128 + n * 16 + l15) * 4 + l4) * 8];
        #pragma unroll
        for (int n = 0; n < 8; ++n)
            acc[n] = __builtin_amdgcn_mfma_f32_16x16x32_bf16(af, bfr[n], acc[n], 0, 0, 0);
        if (wc == 1) {
            short8 pf = *(const short8*)&Wp[l15 * 128 + k0 + l4 * 8];
            pacc = __builtin_amdgcn_mfma_f32_16x16x32_bf16(af, pf, pacc, 0, 0, 0);
        }
        if (t + 1 < 4) { __syncthreads(); stage((t + 1) * 32); }
    }

    __syncthreads();
    #pragma unroll
    for (int n = 0; n < 8; ++n) {
        int col = wc * 128 + n * 16 + l15;
        float bv = b1[col];
        #pragma unroll
        for (int r = 0; r < 4; ++r) {
            int row = wr * 16 + l4 * 4 + r;
            hidL[row * LDPAD + col] = f2b(fmaxf(acc[n][r] + bv, 0.f));
        }
    }
    if (wc == 1) {
        #pragma unroll
        for (int r = 0; r < 4; ++r) {
            int gr = row0 + wr * 16 + l4 * 4 + r;
            if (gr < NN) phi_b[(size_t)gr * 16 + l15] = f2b(pacc[r]);
        }
    }
    __syncthreads();

    f32x4 acc2[2];
    acc2[0] = (f32x4){0.f, 0.f, 0.f, 0.f};
    acc2[1] = (f32x4){0.f, 0.f, 0.f, 0.f};
    for (int kk = 0; kk < 8; ++kk) {
        int k0 = kk * 32;
        short8 a2 = *(const short8*)&hidL[(wr * 16 + l15) * LDPAD + k0 + l4 * 8];
        #pragma unroll
        for (int n = 0; n < 2; ++n) {
            int col = wc * 32 + n * 16 + l15;
            short8 b2f_ = *(const short8*)&W2_bf[(size_t)col * 256 + k0 + l4 * 8];
            acc2[n] = __builtin_amdgcn_mfma_f32_16x16x32_bf16(a2, b2f_, acc2[n], 0, 0, 0);
        }
    }
    float lf = 0.f;
    #pragma unroll
    for (int n = 0; n < 2; ++n) {
        int gc = wc * 32 + n * 16 + l15;
        float bv = b2[gc], tv = tnorm[gc];
        #pragma unroll
        for (int r = 0; r < 4; ++r) {
            int gr = row0 + wr * 16 + l4 * 4 + r;
            if (gr < NN) {
                float v = acc2[n][r] + bv;
                lf += v * v;
                deltap[(size_t)gr * 64 + gc] = f2b(v + tv);
            }
        }
    }
    #pragma unroll
    for (int s = 32; s; s >>= 1) lf += __shfl_xor(lf, s);
    __syncthreads();
    float* red = (float*)&lds[16896];
    if (l == 0) red[w] = lf;
    __syncthreads();
    if (tid == 0) {
        float t_ = 0.f;
        #pragma unroll
        for (int j = 0; j < 8; ++j) t_ += red[j];
        lf_part[bxm] = t_;
    }
}

// ---------------------------------------------------------------------------
// merged dispatch, 512 threads.
//   [0,782)      h-GEMM (dbuf)
//   [782,1564)   hid+phi+delta
//   [1564,1955)  CSR scatter: csr_src[offs[dst]+rank] = (ushort)src (ILP-4)
// ---------------------------------------------------------------------------
__global__ __launch_bounds__(512) void fused3_k(const float* __restrict__ e_l,
                                                const float* __restrict__ h_l,
                                                const unsigned short* __restrict__ W1_bf,
                                                const unsigned short* __restrict__ Wphi_t,
                                                const unsigned short* __restrict__ W_t,
                                                const unsigned short* __restrict__ W2_bf,
                                                const float* __restrict__ b1,
                                                const float* __restrict__ b2,
                                                const float* __restrict__ tnorm,
                                                unsigned short* __restrict__ phi_b,
                                                unsigned int* __restrict__ h8w,
                                                unsigned short* __restrict__ deltap,
                                                float* __restrict__ lf_part,
                                                const int* __restrict__ src,
                                                const int* __restrict__ dst,
                                                const int* __restrict__ rank,
                                                const int* __restrict__ offs,
                                                unsigned short* __restrict__ csr_src) {
    __shared__ __align__(16) unsigned short lds[17408];   // 34.8 KB
    int bx = blockIdx.x;
    if (bx < 782) {
        hgemm8_body(lds, h_l, W_t, h8w, bx >> 1, bx & 1);
    } else if (bx < 1564) {
        hiddelta_body(lds, e_l, W1_bf, Wphi_t, W2_bf, b1, b2, tnorm,
                      phi_b, deltap, lf_part, bx - 782);
    } else {
        int base = (bx - 1564) * 2048 + threadIdx.x;
        int pos[4], sv[4];
        #pragma unroll
        for (int j = 0; j < 4; ++j) {
            int e = base + j * 512;
            if (e < EE) { pos[j] = offs[dst[e]] + rank[e]; sv[j] = src[e]; }
            else pos[j] = -1;
        }
        #pragma unroll
        for (int j = 0; j < 4; ++j)
            if (pos[j] >= 0) csr_src[pos[j]] = (unsigned short)sv[j];
    }
}

// ---------------------------------------------------------------------------
#define SCAN_NB ((NN + 255) / 256)   // 196
#define LF_NB 782

__global__ __launch_bounds__(256) void scan_partial_k(const int* __restrict__ deg,
                                                      int* __restrict__ bsum) {
    __shared__ int ws_[4];
    int i = blockIdx.x * 256 + threadIdx.x;
    int v = (i < NN) ? deg[i] : 0;
    int x = v;
    #pragma unroll
    for (int s = 32; s; s >>= 1) x += __shfl_xor(x, s);
    if ((threadIdx.x & 63) == 0) ws_[threadIdx.x >> 6] = x;
    __syncthreads();
    if (threadIdx.x == 0) bsum[blockIdx.x] = ws_[0] + ws_[1] + ws_[2] + ws_[3];
}

__global__ __launch_bounds__(256) void scan_bsum_k(int* __restrict__ bsum) {
    __shared__ int sd[256];
    int t = threadIdx.x;
    int v = (t < SCAN_NB) ? bsum[t] : 0;
    sd[t] = v;
    __syncthreads();
    for (int s = 1; s < 256; s <<= 1) {
        int u = (t >= s) ? sd[t - s] : 0;
        __syncthreads();
        sd[t] += u;
        __syncthreads();
    }
    if (t < SCAN_NB) bsum[t] = sd[t] - v;   // exclusive
}

__global__ __launch_bounds__(256) void scan_scatter_k(const int* __restrict__ deg,
                                                      const int* __restrict__ bsum,
                                                      int* __restrict__ offs,
                                                      unsigned short* __restrict__ csr_dst) {
    __shared__ int wexc[4];
    int i = blockIdx.x * 256 + threadIdx.x;
    int lane = threadIdx.x & 63, wid = threadIdx.x >> 6;
    int v = (i < NN) ? deg[i] : 0;
    int x = v;
    #pragma unroll
    for (int d = 1; d < 64; d <<= 1) { int u = __shfl_up(x, d); if (lane >= d) x += u; }
    if (lane == 63) wexc[wid] = x;
    __syncthreads();
    if (threadIdx.x == 0) {
        int a = wexc[0], b = wexc[1], c = wexc[2];
        wexc[0] = 0; wexc[1] = a; wexc[2] = a + b; wexc[3] = a + b + c;
    }
    __syncthreads();
    int excl = (x - v) + wexc[wid] + bsum[blockIdx.x];
    if (i < NN) {
        offs[i + 1] = excl + v;
        if (i == 0) offs[0] = 0;
        for (int q = excl; q < excl + v; ++q) csr_dst[q] = (unsigned short)i;
    }
}

// ---------------------------------------------------------------------------
// edge weights (thread per CSR slot); phi & deltap bf16; writes 4x bf16 (8B);
// block 3125 finalizes l_focus.
// ---------------------------------------------------------------------------
__global__ __launch_bounds__(256) void edge_w_k(const unsigned short* __restrict__ csr_src,
                                                const unsigned short* __restrict__ csr_dst,
                                                const unsigned short* __restrict__ phi_b,
                                                const unsigned short* __restrict__ deltap,
                                                uint2* __restrict__ csr_wb,
                                                const float* __restrict__ lfocus_part,
                                                float* __restrict__ lfocus_out) {
    if (blockIdx.x == 3125) {
        __shared__ float red[4];
        float s = 0.f;
        for (int i = threadIdx.x; i < LF_NB; i += 256) s += lfocus_part[i];
        #pragma unroll
        for (int st = 32; st; st >>= 1) s += __shfl_xor(s, st);
        if ((threadIdx.x & 63) == 0) red[threadIdx.x >> 6] = s;
        __syncthreads();
        if (threadIdx.x == 0)
            lfocus_out[0] = (red[0] + red[1] + red[2] + red[3]) * (1.f / ((float)NN * 4));
        return;
    }
    int e = blockIdx.x * 256 + threadIdx.x;
    if (e >= EE) return;
    int s = csr_src[e], d = csr_dst[e];
    float pv[16], qv[16];
    {
        const uint4* P = (const uint4*)(phi_b + (size_t)s * 16);
        uint4 x0 = P[0], x1 = P[1];
        unsigned xs[8] = {x0.x, x0.y, x0.z, x0.w, x1.x, x1.y, x1.z, x1.w};
        #pragma unroll
        for (int j = 0; j < 8; ++j) { pv[2 * j] = b2f(xs[j]); pv[2 * j + 1] = b2f(xs[j] >> 16); }
        const uint4* Q = (const uint4*)(phi_b + (size_t)d * 16);
        uint4 y0 = Q[0], y1 = Q[1];
        unsigned ys[8] = {y0.x, y0.y, y0.z, y0.w, y1.x, y1.y, y1.z, y1.w};
        #pragma unroll
        for (int j = 0; j < 8; ++j) { qv[2 * j] = b2f(ys[j]); qv[2 * j + 1] = b2f(ys[j] >> 16); }
    }
    float dv[16];
    float nrm2 = 0.f;
    #pragma unroll
    for (int p = 0; p < 15; ++p) {
        dv[p] = pv[p] - qv[p];
        nrm2 += dv[p] * dv[p];
    }
    float z = (nrm2 == 0.f) ? 1.f : 0.f;
    dv[15] = z;
    nrm2 += z;
    float inv = 1.f / fmaxf(sqrtf(nrm2), 1e-8f);
    const uint2* dl2 = (const uint2*)(deltap + (size_t)d * 64);
    float res[4];
    #pragma unroll
    for (int k = 0; k < 4; ++k) {
        float sacc = 0.f;
        #pragma unroll
        for (int q = 0; q < 4; ++q) {
            uint2 u = dl2[k * 4 + q];
            sacc += dv[q * 4 + 0] * b2f(u.x) + dv[q * 4 + 1] * b2f(u.x >> 16)
                  + dv[q * 4 + 2] * b2f(u.y) + dv[q * 4 + 3] * b2f(u.y >> 16);
        }
        res[k] = __expf(sacc * inv);
    }
    csr_wb[e] = make_uint2(cvt_pk_bf16(res[0], res[1]), cvt_pk_bf16(res[2], res[3]));
}

// ---------------------------------------------------------------------------
// per-dst aggregation, wave per node, lane = channel. csr_w is 4x bf16/edge.
// Wave-uniform weights/indices scalarized via readfirstlane.
// ---------------------------------------------------------------------------
__global__ __launch_bounds__(256) void aggregate_k(const int* __restrict__ offs,
                                                   const unsigned short* __restrict__ csr_src,
                                                   const unsigned int* __restrict__ csr_wu,
                                                   const unsigned int* __restrict__ h8,
                                                   const float* __restrict__ bias,
                                                   float* __restrict__ out) {
    int wave = threadIdx.x >> 6;
    int lane = threadIdx.x & 63;
    int n = blockIdx.x * 4 + wave;
    if (n >= NN) return;
    int beg = offs[n], end = offs[n + 1];

    // phase 1: denominators (coalesced flat read; uint parity = k-class pair)
    float pA = 0.f, pB = 0.f;
    for (int q = beg * 2 + lane; q < end * 2; q += 64) {
        unsigned u = csr_wu[q];
        pA += b2f(u);
        pB += b2f(u >> 16);
    }
    #pragma unroll
    for (int s = 2; s < 64; s <<= 1) { pA += __shfl_xor(pA, s); pB += __shfl_xor(pB, s); }
    float iA = (pA > 0.f) ? 1.f / pA : 0.f;
    float iB = (pB > 0.f) ? 1.f / pB : 0.f;
    float i0 = __shfl(iA, 0), i1 = __shfl(iB, 0);
    float i2 = __shfl(iA, 1), i3 = __shfl(iB, 1);

    // phase 2: weighted accumulation; weights & src idx scalarized
    const uint2* csr_w2 = (const uint2*)csr_wu;
    float a0 = 0.f, a1 = 0.f, a2 = 0.f, a3 = 0.f;
    int p = beg;
    for (; p + 3 < end; p += 4) {
        uint2 u0 = csr_w2[p], u1 = csr_w2[p + 1], u2 = csr_w2[p + 2], u3 = csr_w2[p + 3];
        int t0 = __builtin_amdgcn_readfirstlane((int)csr_src[p]);
        int t1 = __builtin_amdgcn_readfirstlane((int)csr_src[p + 1]);
        int t2 = __builtin_amdgcn_readfirstlane((int)csr_src[p + 2]);
        int t3 = __builtin_amdgcn_readfirstlane((int)csr_src[p + 3]);
        unsigned w0x = __builtin_amdgcn_readfirstlane(u0.x);
        unsigned w0y = __builtin_amdgcn_readfirstlane(u0.y);
        unsigned w1x = __builtin_amdgcn_readfirstlane(u1.x);
        unsigned w1y = __builtin_amdgcn_readfirstlane(u1.y);
        unsigned w2x = __builtin_amdgcn_readfirstlane(u2.x);
        unsigned w2y = __builtin_amdgcn_readfirstlane(u2.y);
        unsigned w3x = __builtin_amdgcn_readfirstlane(u3.x);
        unsigned w3y = __builtin_amdgcn_readfirstlane(u3.y);
        unsigned hv0 = h8[(size_t)t0 * 64 + lane];
        unsigned hv1 = h8[(size_t)t1 * 64 + lane];
        unsigned hv2 = h8[(size_t)t2 * 64 + lane];
        unsigned hv3 = h8[(size_t)t3 * 64 + lane];
        f32x2 lo, hi;
        lo = __builtin_amdgcn_cvt_pk_f32_fp8(hv0, false);
        hi = __builtin_amdgcn_cvt_pk_f32_fp8(hv0, true);
        a0 += b2f(w0x) * lo.x; a1 += b2f(w0x >> 16) * lo.y;
        a2 += b2f(w0y) * hi.x; a3 += b2f(w0y >> 16) * hi.y;
        lo = __builtin_amdgcn_cvt_pk_f32_fp8(hv1, false);
        hi = __builtin_amdgcn_cvt_pk_f32_fp8(hv1, true);
        a0 += b2f(w1x) * lo.x; a1 += b2f(w1x >> 16) * lo.y;
        a2 += b2f(w1y) * hi.x; a3 += b2f(w1y >> 16) * hi.y;
        lo = __builtin_amdgcn_cvt_pk_f32_fp8(hv2, false);
        hi = __builtin_amdgcn_cvt_pk_f32_fp8(hv2, true);
        a0 += b2f(w2x) * lo.x; a1 += b2f(w2x >> 16) * lo.y;
        a2 += b2f(w2y) * hi.x; a3 += b2f(w2y >> 16) * hi.y;
        lo = __builtin_amdgcn_cvt_pk_f32_fp8(hv3, false);
        hi = __builtin_amdgcn_cvt_pk_f32_fp8(hv3, true);
        a0 += b2f(w3x) * lo.x; a1 += b2f(w3x >> 16) * lo.y;
        a2 += b2f(w3y) * hi.x; a3 += b2f(w3y >> 16) * hi.y;
    }
    for (; p < end; ++p) {
        uint2 uA = csr_w2[p];
        int tA = __builtin_amdgcn_readfirstlane((int)csr_src[p]);
        unsigned wAx = __builtin_amdgcn_readfirstlane(uA.x);
        unsigned wAy = __builtin_amdgcn_readfirstlane(uA.y);
        unsigned hv = h8[(size_t)tA * 64 + lane];
        f32x2 lo = __builtin_amdgcn_cvt_pk_f32_fp8(hv, false);
        f32x2 hi = __builtin_amdgcn_cvt_pk_f32_fp8(hv, true);
        a0 += b2f(wAx) * lo.x; a1 += b2f(wAx >> 16) * lo.y;
        a2 += b2f(wAy) * hi.x; a3 += b2f(wAy >> 16) * hi.y;
    }
    float v = a0 * i0 + a1 * i1 + a2 * i2 + a3 * i3 + bias[lane];
    float nr = v * v;
    #pragma unroll
    for (int s = 32; s; s >>= 1) nr += __shfl_xor(nr, s);
    float invn = 1.f / fmaxf(sqrtf(nr), 1e-8f);
    out[(size_t)n * 64 + lane] = v * invn;
}

// ---------------------------------------------------------------------------
extern "C" void kernel_launch(void* const* d_in, const int* in_sizes, int n_in,
                              void* d_out, int out_size, void* d_ws, size_t ws_size,
                              hipStream_t stream) {
    const float* h_l       = (const float*)d_in[0];
    const float* e_l       = (const float*)d_in[1];
    const int*   src       = (const int*)d_in[2];
    const int*   dst       = (const int*)d_in[3];
    const float* W_phi     = (const float*)d_in[4];
    const float* W1        = (const float*)d_in[5];
    const float* b1        = (const float*)d_in[6];
    const float* W2        = (const float*)d_in[7];
    const float* b2        = (const float*)d_in[8];
    const float* tilde_phi = (const float*)d_in[9];
    const float* W         = (const float*)d_in[10];
    const float* bias      = (const float*)d_in[11];
    float* out = (float*)d_out;
    float* lsep_ptr   = out + (size_t)NN * 64;
    float* lfocus_ptr = out + (size_t)NN * 64 + 1;

    char* ws = (char*)d_ws;
    size_t off = 0;
    auto alloc = [&](size_t bytes) -> char* {
        char* p = ws + off;
        off += (bytes + 255) & ~(size_t)255;
        return p;
    };
    unsigned short* phi_b   = (unsigned short*)alloc((size_t)NN * 16 * 2);
    unsigned short* deltap  = (unsigned short*)alloc((size_t)NN * 64 * 2);
    unsigned int*   h8w     = (unsigned int*)alloc((size_t)NN * 256);
    unsigned short* csr_src = (unsigned short*)alloc((size_t)EE * 2);
    unsigned short* csr_dst = (unsigned short*)alloc((size_t)EE * 2);
    int*            rank    = (int*)alloc((size_t)EE * 4);
    uint2*          csr_wb  = (uint2*)alloc((size_t)EE * 8);
    int*            deg     = (int*)alloc((size_t)NN * 4);
    int*            offs    = (int*)alloc((size_t)(NN + 1) * 4);
    int*            bsum    = (int*)alloc((size_t)SCAN_NB * 4);
    float*          lf_part = (float*)alloc((size_t)LF_NB * 4);
    unsigned short* W_t     = (unsigned short*)alloc(256 * 256 * 2);
    unsigned short* W1_bf   = (unsigned short*)alloc(256 * 128 * 2);
    unsigned short* W2_bf   = (unsigned short*)alloc(64 * 256 * 2);
    unsigned short* Wphi_t  = (unsigned short*)alloc(16 * 128 * 2);
    float*          tnorm   = (float*)alloc(64 * 4);

    hipMemsetAsync(deg, 0, (size_t)NN * 4, stream);

    // prep: rank/degree atomics + weight prep + tnorm/lsep
    prep_k<<<(PREP_THREADS + 255) / 256, 256, 0, stream>>>(
        W, W1, W2, W_phi, tilde_phi, dst,
        W_t, W1_bf, W2_bf, Wphi_t, deg, rank, tnorm, lsep_ptr);

    // CSR offsets (+ contiguous ushort csr_dst fill)
    scan_partial_k<<<SCAN_NB, 256, 0, stream>>>(deg, bsum);
    scan_bsum_k<<<1, 256, 0, stream>>>(bsum);
    scan_scatter_k<<<SCAN_NB, 256, 0, stream>>>(deg, bsum, offs, csr_dst);

    // merged: h-GEMM (dbuf) + hid+phi+delta + ushort scatter
    fused3_k<<<1955, 512, 0, stream>>>(e_l, h_l, W1_bf, Wphi_t, W_t, W2_bf,
                                       b1, b2, tnorm, phi_b, h8w, deltap, lf_part,
                                       src, dst, rank, offs, csr_src);

    // edge weights (bf16 phi/delta, bf16-packed out) + l_focus finalize
    edge_w_k<<<3126, 256, 0, stream>>>(csr_src, csr_dst, phi_b, deltap, csr_wb,
                                       lf_part, lfocus_ptr);

    // per-dst softmax + aggregation + normalize
    aggregate_k<<<12500, 256, 0, stream>>>(offs, csr_src, (const unsigned int*)csr_wb,
                                           h8w, bias, out);
}